// Round 22
// baseline (55.747 us; speedup 1.0000x reference)
//
#include <hip/hip_runtime.h>
#include <hip/hip_bf16.h>

#define N      8192
#define D_IN   30
#define HID    32
#define D_OUT  30
#define FFD    128
#define ZC     34
#define JGC    16     // j-split groups
#define NCH    4      // chunks per jg (compile-time -> full unroll)

typedef __attribute__((ext_vector_type(8))) short short8;
typedef __attribute__((ext_vector_type(16))) float f32x16;

static __device__ __forceinline__ ushort f2bf(float x) {
    uint32_t u = __float_as_uint(x);
    uint32_t r = (u + 0x7fffu + ((u >> 16) & 1u)) >> 16;   // RTNE
    return (ushort)r;
}
static __device__ __forceinline__ float bf2f(ushort u) {
    return __uint_as_float(((uint32_t)u) << 16);
}
static __device__ __forceinline__ float rdlane(float v, int l) {
    return __uint_as_float(__builtin_amdgcn_readlane(__float_as_uint(v), l));
}

// ---------------------------------------------------------------------------
// Kernel A (R14-identical): QKV -> bf16; VWo^T (row30=0,row31=1 -> PV col31
// = rowsum); negated split-bf16 gate tables (gate MFMA = +D); W2e = W2@We,
// b2e = b2@We + be.
// ---------------------------------------------------------------------------
__global__ __launch_bounds__(256) void dv_qkv_kernel(
    const float* __restrict__ Z,
    const float* __restrict__ Wq, const float* __restrict__ bq,
    const float* __restrict__ Wk, const float* __restrict__ bk,
    const float* __restrict__ Wv, const float* __restrict__ bv,
    const float* __restrict__ Wo,
    const float* __restrict__ W2, const float* __restrict__ We,
    const float* __restrict__ b2, const float* __restrict__ be,
    ushort* __restrict__ Qb, ushort* __restrict__ Kb,
    ushort* __restrict__ VWot, ushort* __restrict__ KA,
    ushort* __restrict__ QB, float* __restrict__ W2e, float* __restrict__ b2e)
{
    __shared__ ushort sv[8][33];
    const int t = blockIdx.x * 256 + threadIdx.x;
    const int i = t >> 5;
    const int h = t & 31;
    const float* z = Z + (size_t)i * ZC;

    float q = bq[h], k = bk[h], v = bv[h];
#pragma unroll
    for (int d = 0; d < D_IN; ++d) {
        float zf = z[d];
        q = fmaf(zf, Wq[d * HID + h], q);
        k = fmaf(zf, Wk[d * HID + h], k);
        v = fmaf(zf, Wv[d * HID + h], v);
    }
    const float QS = 0.17677669529663687f * 1.4426950408889634f; // log2e/sqrt(32)
    Qb[(size_t)i * HID + h] = f2bf(q * QS);
    Kb[(size_t)i * HID + h] = f2bf(k);
    sv[threadIdx.x >> 5][h] = f2bf(v);

    if (h == 0) {
        float p0 = z[D_IN], p1 = z[D_IN + 1], p2 = z[D_IN + 2];
        const float C2 = 1.4426950408889634f / 0.18f;   // log2e/(2*sigma^2)
        const float SC = sqrtf(2.0f * C2);
        float px = p0 * SC, py = p1 * SC, pz = p2 * SC;
        float w  = -C2 * (p0 * p0 + p1 * p1 + p2 * p2);
        ushort phx = f2bf(px), phy = f2bf(py), phz = f2bf(pz);
        ushort plx = f2bf(px - bf2f(phx));
        ushort ply = f2bf(py - bf2f(phy));
        ushort plz = f2bf(pz - bf2f(phz));
        ushort wh  = f2bf(w);
        ushort wl  = f2bf(w - bf2f(wh));
        // negate j-side (KA) => MFMA result = +D
        ushort nhx = phx ^ 0x8000, nhy = phy ^ 0x8000, nhz = phz ^ 0x8000;
        ushort nlx = plx ^ 0x8000, nly = ply ^ 0x8000, nlz = plz ^ 0x8000;
        ushort nwh = wh ^ 0x8000,  nwl = wl ^ 0x8000;
        const ushort one = 0x3F80, none = 0xBF80;
        ushort ka0[8] = {nwh, nwl, none, none, nhx, nhy, nhz, nhx};
        ushort ka1[8] = {nhy, nhz, nlx, nly, nlz, nlx, nly, nlz};
        ushort qb0[8] = {one, one, wh, wl, phx, phy, phz, plx};
        ushort qb1[8] = {ply, plz, phx, phy, phz, plx, ply, plz};
        *(uint4*)&KA[(size_t)i * 8]       = *(uint4*)ka0;
        *(uint4*)&KA[((size_t)N + i) * 8] = *(uint4*)ka1;
        *(uint4*)&QB[(size_t)i * 8]       = *(uint4*)qb0;
        *(uint4*)&QB[((size_t)N + i) * 8] = *(uint4*)qb1;
    }

    // W2e = W2 @ We  (+ b2e) over the first 15 blocks
    if (blockIdx.x < 15) {
        int idx = blockIdx.x * 256 + threadIdx.x;      // 0..3839
        int f = idx / 30, o = idx - f * 30;
        float acc = 0.f;
#pragma unroll
        for (int d = 0; d < D_OUT; ++d)
            acc = fmaf(W2[f * D_OUT + d], We[d * D_OUT + o], acc);
        W2e[idx] = acc;
        if (idx < D_OUT) {
            float a2 = be[idx];
#pragma unroll
            for (int d = 0; d < D_OUT; ++d)
                a2 = fmaf(b2[d], We[d * D_OUT + idx], a2);
            b2e[idx] = a2;
        }
    }

    __syncthreads();
    // VWo^T: row c (0..29) = (V@Wo) col c; row 30 = 0; row 31 = 1.0
    const int io = threadIdx.x >> 5, c = threadIdx.x & 31;
    const int ii = blockIdx.x * 8 + io;
    float val;
    if (c < 30) {
        float acc = 0.f;
#pragma unroll
        for (int hh = 0; hh < HID; ++hh)
            acc = fmaf(bf2f(sv[io][hh]), Wo[hh * D_OUT + c], acc);
        val = acc;
    } else {
        val = (c == 31) ? 1.0f : 0.f;
    }
    VWot[(size_t)c * N + ii] = f2bf(val);
}

// ---------------------------------------------------------------------------
// Kernel B: R21 attention (dbuf LDS, reg prefetch, bounded gate, bf16
// partial, setprio) + WAVE COARSENING: each wave owns TWO i-tiles
// (i0A = rb*256 + wv*32, i0B = i0A+128) -> two independent MFMA->gate->PV
// dependency chains per tile for 2x ILP; K/V/KA LDS tiles shared by both.
// Grid 32 rb x JGC = 512 blocks.
// ---------------------------------------------------------------------------
__global__ __launch_bounds__(256, 2) void dv_attn_kernel(
    const ushort* __restrict__ Qb, const ushort* __restrict__ Kb,
    const ushort* __restrict__ VWot, const ushort* __restrict__ KA,
    const ushort* __restrict__ QB, ushort* __restrict__ partial)
{
    __shared__ ushort lK[2][128 * 32];    // K tiles, 16B-chunk rot swizzle
    __shared__ ushort lV[2][32 * 128];    // VWo^T tiles, 8B-chunk XOR swizzle
    __shared__ ushort lKA[2][2][128 * 8]; // gate A-side aug

    const int tid  = threadIdx.x;
    const int lane = tid & 63;
    const int wv   = tid >> 6;
    const int h2   = lane >> 5;
    const int l31  = lane & 31;
    const int rb   = blockIdx.x & 31;
    const int jg   = blockIdx.x >> 5;
    const int i0A  = rb * 256 + wv * 32;
    const int i0B  = i0A + 128;

    const ushort* qpA = Qb + (size_t)(i0A + l31) * HID + h2 * 8;
    const short8 qf0A = *(const short8*)qpA;
    const short8 qf1A = *(const short8*)(qpA + 16);
    const short8 qaugA = *(const short8*)&QB[((size_t)h2 * N + i0A + l31) * 8];
    const ushort* qpB = Qb + (size_t)(i0B + l31) * HID + h2 * 8;
    const short8 qf0B = *(const short8*)qpB;
    const short8 qf1B = *(const short8*)(qpB + 16);
    const short8 qaugB = *(const short8*)&QB[((size_t)h2 * N + i0B + l31) * 8];

    f32x16 zacc, oaccA, oaccB;
#pragma unroll
    for (int r = 0; r < 16; ++r) { zacc[r] = 0.f; oaccA[r] = 0.f; oaccB[r] = 0.f; }

    const int cA0 = (h2 + (l31 >> 1)) & 3;
    const int cA1 = (cA0 + 2) & 3;

    // staging indices (fixed per thread)
    const int kjr0 = tid >> 2,          kcc0 = tid & 3;
    const int kjr1 = (tid + 256) >> 2,  kcc1 = (tid + 256) & 3;
    const int kc20 = (kcc0 + (kjr0 >> 1)) & 3;
    const int kc21 = (kcc1 + (kjr1 >> 1)) & 3;
    const int vhh[4] = { tid >> 5, (tid + 256) >> 5, (tid + 512) >> 5, (tid + 768) >> 5 };
    const int vcx = tid & 31;
    const int ahalf = tid >> 7, ajj = tid & 127;

    uint4 kreg[2];
    uint2 vreg[4];
    uint4 kareg;

    auto LOADC = [&](int c) {
        const int j0 = (jg * NCH + c) << 7;
        kreg[0] = *(const uint4*)&Kb[(size_t)(j0 + kjr0) * HID + kcc0 * 8];
        kreg[1] = *(const uint4*)&Kb[(size_t)(j0 + kjr1) * HID + kcc1 * 8];
#pragma unroll
        for (int r2 = 0; r2 < 4; ++r2)
            vreg[r2] = *(const uint2*)&VWot[(size_t)vhh[r2] * N + j0 + vcx * 4];
        kareg = *(const uint4*)&KA[((size_t)ahalf * N + j0 + ajj) * 8];
    };
    auto WRITEC = [&](int b) {
        *(uint4*)&lK[b][kjr0 * 32 + kc20 * 8] = kreg[0];
        *(uint4*)&lK[b][kjr1 * 32 + kc21 * 8] = kreg[1];
#pragma unroll
        for (int r2 = 0; r2 < 4; ++r2)
            *(uint2*)&lV[b][vhh[r2] * 128 + (vcx ^ vhh[r2]) * 4] = vreg[r2];
        *(uint4*)&lKA[b][ahalf][ajj * 8] = kareg;
    };

    // prologue: chunk 0 -> buf 0
    LOADC(0);
    WRITEC(0);

#pragma unroll
    for (int ch = 0; ch < NCH; ++ch) {
        const int cur = ch & 1;
        if (ch + 1 < NCH) LOADC(ch + 1);   // issue early; lands under compute
        __syncthreads();                    // buf[cur] ready; prev reads done

        __builtin_amdgcn_s_setprio(1);
#pragma unroll
        for (int t32 = 0; t32 < 4; ++t32) {
            const ushort* krow = &lK[cur][(t32 * 32 + l31) * 32];
            short8 kf0 = *(const short8*)&krow[cA0 * 8];
            short8 kf1 = *(const short8*)&krow[cA1 * 8];
            short8 kaug = *(const short8*)&lKA[cur][h2][(t32 * 32 + l31) * 8];

            // two independent score/gate chains (A and B)
            f32x16 sA = __builtin_amdgcn_mfma_f32_32x32x16_bf16(kf0, qf0A, zacc, 0, 0, 0);
            f32x16 sB = __builtin_amdgcn_mfma_f32_32x32x16_bf16(kf0, qf0B, zacc, 0, 0, 0);
            sA = __builtin_amdgcn_mfma_f32_32x32x16_bf16(kf1, qf1A, sA, 0, 0, 0);
            sB = __builtin_amdgcn_mfma_f32_32x32x16_bf16(kf1, qf1B, sB, 0, 0, 0);
            f32x16 gAA = __builtin_amdgcn_mfma_f32_32x32x16_bf16(kaug, qaugA, zacc, 0, 0, 0);
            f32x16 gAB = __builtin_amdgcn_mfma_f32_32x32x16_bf16(kaug, qaugB, zacc, 0, 0, 0);

            uint32_t pkA[8], pkB[8];
#pragma unroll
            for (int p = 0; p < 8; ++p) {
                // a = 2^-D * rcp(1 + 2^-S'); D >= -eps, all factors bounded
                float egA0 = __builtin_amdgcn_exp2f(-gAA[2 * p]);
                float esA0 = __builtin_amdgcn_exp2f(-sA[2 * p]);
                float aA0  = egA0 * __builtin_amdgcn_rcpf(1.0f + esA0);
                float egA1 = __builtin_amdgcn_exp2f(-gAA[2 * p + 1]);
                float esA1 = __builtin_amdgcn_exp2f(-sA[2 * p + 1]);
                float aA1  = egA1 * __builtin_amdgcn_rcpf(1.0f + esA1);
                asm("v_cvt_pk_bf16_f32 %0, %1, %2" : "=v"(pkA[p]) : "v"(aA0), "v"(aA1));
                float egB0 = __builtin_amdgcn_exp2f(-gAB[2 * p]);
                float esB0 = __builtin_amdgcn_exp2f(-sB[2 * p]);
                float aB0  = egB0 * __builtin_amdgcn_rcpf(1.0f + esB0);
                float egB1 = __builtin_amdgcn_exp2f(-gAB[2 * p + 1]);
                float esB1 = __builtin_amdgcn_exp2f(-sB[2 * p + 1]);
                float aB1  = egB1 * __builtin_amdgcn_rcpf(1.0f + esB1);
                asm("v_cvt_pk_bf16_f32 %0, %1, %2" : "=v"(pkB[p]) : "v"(aB0), "v"(aB1));
            }
            union BV { uint32_t u[4]; short8 v; };
            BV faA, fbA, faB, fbB;
            faA.u[0] = pkA[0]; faA.u[1] = pkA[1]; faA.u[2] = pkA[2]; faA.u[3] = pkA[3];
            fbA.u[0] = pkA[4]; fbA.u[1] = pkA[5]; fbA.u[2] = pkA[6]; fbA.u[3] = pkA[7];
            faB.u[0] = pkB[0]; faB.u[1] = pkB[1]; faB.u[2] = pkB[2]; faB.u[3] = pkB[3];
            fbB.u[0] = pkB[4]; fbB.u[1] = pkB[5]; fbB.u[2] = pkB[6]; fbB.u[3] = pkB[7];

            // V fragments shared by A and B
            const ushort* vrow = &lV[cur][l31 * 128];
            const int cb = t32 * 8 + h2;
            BV b0, b1;
            *(uint2*)&b0.u[0] = *(const uint2*)&vrow[((cb    ) ^ l31) * 4];
            *(uint2*)&b0.u[2] = *(const uint2*)&vrow[((cb + 2) ^ l31) * 4];
            *(uint2*)&b1.u[0] = *(const uint2*)&vrow[((cb + 4) ^ l31) * 4];
            *(uint2*)&b1.u[2] = *(const uint2*)&vrow[((cb + 6) ^ l31) * 4];

            oaccA = __builtin_amdgcn_mfma_f32_32x32x16_bf16(faA.v, b0.v, oaccA, 0, 0, 0);
            oaccB = __builtin_amdgcn_mfma_f32_32x32x16_bf16(faB.v, b0.v, oaccB, 0, 0, 0);
            oaccA = __builtin_amdgcn_mfma_f32_32x32x16_bf16(fbA.v, b1.v, oaccA, 0, 0, 0);
            oaccB = __builtin_amdgcn_mfma_f32_32x32x16_bf16(fbB.v, b1.v, oaccB, 0, 0, 0);
        }
        __builtin_amdgcn_s_setprio(0);

        if (ch + 1 < NCH) WRITEC(cur ^ 1);  // fill other buffer; overlaps
    }

    // partial[i][jg*32 + c] (bf16): c<30 = raw pre-Wo H, c==31 = rowsum
#pragma unroll
    for (int r = 0; r < 16; ++r) {
        int ro = (r & 3) + 8 * (r >> 2) + 4 * h2;
        partial[(size_t)(i0A + ro) * (JGC * 32) + jg * 32 + l31] = f2bf(oaccA[r]);
        partial[(size_t)(i0B + ro) * (JGC * 32) + jg * 32 + l31] = f2bf(oaccB[r]);
    }
}

// ---------------------------------------------------------------------------
// Kernel C (R19-identical): epilogue v4 — wave-per-row, zero __syncthreads,
// bf16 partial in.
// ---------------------------------------------------------------------------
__global__ __launch_bounds__(256) void dv_epilogue_kernel(
    const ushort* __restrict__ partial,
    const float* __restrict__ bo,
    const float* __restrict__ ln_g, const float* __restrict__ ln_b,
    const float* __restrict__ W1, const float* __restrict__ b1,
    const float* __restrict__ W2e, const float* __restrict__ b2e,
    float* __restrict__ out)
{
    __shared__ float shf[4][FFD];    // per-wave private silu slice

    const int tid  = threadIdx.x;
    const int wv   = tid >> 6;
    const int lane = tid & 63;
    const int row  = blockIdx.x * 4 + wv;
    const int c    = lane & 31;
    const int half = lane >> 5;
    const bool a30 = c < 30;
    const int  c30 = a30 ? c : 0;

    // P1: row's 512 bf16 partials; lane reads 8 (stride 64), fold lane^32.
    float s8 = 0.f;
    {
        const ushort* pp = partial + (size_t)row * (JGC * 32) + lane;
#pragma unroll
        for (int q = 0; q < 8; ++q) s8 += bf2f(pp[q * 64]);
    }
    float sv = s8 + __shfl_xor(s8, 32, 64);   // col sums, dup in both halves

    float rsum = __shfl(sv, 31, 32);          // col 31 = rowsum
    float inv  = __builtin_amdgcn_rcpf(rsum + 1e-8f);
    float Hl   = a30 ? fmaf(sv, inv, bo[c30]) : 0.f;

    // LayerNorm in-register (width-32; lanes with c>=30 contribute 0)
    float x = Hl;
#pragma unroll
    for (int m = 1; m < 32; m <<= 1) x += __shfl_xor(x, m, 32);
    float mu = x * (1.0f / D_OUT);
    float d  = a30 ? (Hl - mu) : 0.f;
    float v2 = d * d;
#pragma unroll
    for (int m = 1; m < 32; m <<= 1) v2 += __shfl_xor(v2, m, 32);
    float rs = rsqrtf(v2 * (1.0f / D_OUT) + 1e-5f);
    float Hn = fmaf(d * rs, ln_g[c30], ln_b[c30]);  // valid where a30

    // FFN1 + SiLU: lane owns f = lane and f = lane + 64 (coalesced W1 rows)
    float acc0 = b1[lane], acc1 = b1[lane + 64];
#pragma unroll
    for (int o = 0; o < D_OUT; ++o) {
        float ho = rdlane(Hn, o);             // lane o < 30 holds Hn[o]
        acc0 = fmaf(ho, W1[o * FFD + lane], acc0);
        acc1 = fmaf(ho, W1[o * FFD + lane + 64], acc1);
    }
    const float L2E = 1.4426950408889634f;
    shf[wv][lane] =
        acc0 * __builtin_amdgcn_rcpf(1.0f + __builtin_amdgcn_exp2f(-acc0 * L2E));
    shf[wv][lane + 64] =
        acc1 * __builtin_amdgcn_rcpf(1.0f + __builtin_amdgcn_exp2f(-acc1 * L2E));
    // same-wave ds_write -> ds_read: ordered by lgkmcnt, no barrier needed

    // FFN2e: half-wave h covers f in [h*64, h*64+64); o = c30 per lane.
    float acc = 0.f;
    {
        const float* hbase = &shf[wv][half * 64];
#pragma unroll
        for (int k = 0; k < 16; ++k) {
            float4 hv = *(const float4*)&hbase[k * 4];
            const int f0 = half * 64 + k * 4;
            acc = fmaf(hv.x, W2e[(f0    ) * D_OUT + c30], acc);
            acc = fmaf(hv.y, W2e[(f0 + 1) * D_OUT + c30], acc);
            acc = fmaf(hv.z, W2e[(f0 + 2) * D_OUT + c30], acc);
            acc = fmaf(hv.w, W2e[(f0 + 3) * D_OUT + c30], acc);
        }
    }
    float val = acc + __shfl_xor(acc, 32, 64) + b2e[c30];

    if (lane < 32 && a30)
        out[(size_t)row * ZC + c] = val;

    float kep = (a30 && half == 0) ? val * val : 0.f;
#pragma unroll
    for (int m = 1; m < 32; m <<= 1) kep += __shfl_xor(kep, m, 32);
    if (lane == 0) {
        float* op = out + (size_t)row * ZC;
        op[30] = 0.f; op[31] = 0.f; op[32] = 0.f;
        op[33] = kep * (0.5f / D_OUT);
    }
}

// ---------------------------------------------------------------------------
extern "C" void kernel_launch(void* const* d_in, const int* in_sizes, int n_in,
                              void* d_out, int out_size, void* d_ws, size_t ws_size,
                              hipStream_t stream)
{
    const float* Z  = (const float*)d_in[1];
    const float* Wq = (const float*)d_in[2];
    const float* bq = (const float*)d_in[3];
    const float* Wk = (const float*)d_in[4];
    const float* bk = (const float*)d_in[5];
    const float* Wv = (const float*)d_in[6];
    const float* bv = (const float*)d_in[7];
    const float* Wo = (const float*)d_in[8];
    const float* bo = (const float*)d_in[9];
    const float* lg = (const float*)d_in[10];
    const float* lb = (const float*)d_in[11];
    const float* W1 = (const float*)d_in[12];
    const float* b1 = (const float*)d_in[13];
    const float* W2 = (const float*)d_in[14];
    const float* b2 = (const float*)d_in[15];
    const float* We = (const float*)d_in[16];
    const float* be = (const float*)d_in[17];
    float* out = (float*)d_out;

    ushort* Qb   = (ushort*)d_ws;                 // N*32 bf16
    ushort* Kb   = Qb + (size_t)N * HID;          // N*32 bf16
    ushort* VWot = Kb + (size_t)N * HID;          // [32][N] bf16 (V@Wo)^T
    ushort* KA   = VWot + (size_t)N * HID;        // [2][N][8] bf16
    ushort* QB   = KA + (size_t)N * 16;           // [2][N][8] bf16
    float*  W2e  = (float*)(QB + (size_t)N * 16); // [128][30]
    float*  b2e  = W2e + FFD * D_OUT;             // [30] (+pad)
    ushort* partial = (ushort*)(b2e + 32);        // [N][JGC*32] bf16

    hipLaunchKernelGGL(dv_qkv_kernel, dim3((N * HID) / 256), dim3(256), 0, stream,
                       Z, Wq, bq, Wk, bk, Wv, bv, Wo, W2, We, b2, be,
                       Qb, Kb, VWot, KA, QB, W2e, b2e);
    hipLaunchKernelGGL(dv_attn_kernel, dim3(32 * JGC), dim3(256), 0, stream,
                       Qb, Kb, VWot, KA, QB, partial);
    hipLaunchKernelGGL(dv_epilogue_kernel, dim3(N / 4), dim3(256), 0, stream,
                       partial, bo, lg, lb, W1, b1, W2e, b2e, out);
}

// Round 23
// 55.281 us; speedup vs baseline: 1.0084x; 1.0084x over previous
//
#include <hip/hip_runtime.h>
#include <hip/hip_bf16.h>

#define N      8192
#define D_IN   30
#define HID    32
#define D_OUT  30
#define FFD    128
#define ZC     34
#define JGC    16     // j-split groups
#define NCH    4      // chunks per jg (compile-time -> full unroll)

typedef __attribute__((ext_vector_type(8))) short short8;
typedef __attribute__((ext_vector_type(16))) float f32x16;

static __device__ __forceinline__ ushort f2bf(float x) {
    uint32_t u = __float_as_uint(x);
    uint32_t r = (u + 0x7fffu + ((u >> 16) & 1u)) >> 16;   // RTNE
    return (ushort)r;
}
static __device__ __forceinline__ float bf2f(ushort u) {
    return __uint_as_float(((uint32_t)u) << 16);
}
static __device__ __forceinline__ float rdlane(float v, int l) {
    return __uint_as_float(__builtin_amdgcn_readlane(__float_as_uint(v), l));
}

// ---------------------------------------------------------------------------
// Kernel A: QKV -> bf16; VWo^T (row30=0,row31=1 -> PV col31 = rowsum);
// negated split-bf16 gate tables (gate MFMA = +D); W2e = W2@We,
// b2e = b2@We + be.
// ---------------------------------------------------------------------------
__global__ __launch_bounds__(256) void dv_qkv_kernel(
    const float* __restrict__ Z,
    const float* __restrict__ Wq, const float* __restrict__ bq,
    const float* __restrict__ Wk, const float* __restrict__ bk,
    const float* __restrict__ Wv, const float* __restrict__ bv,
    const float* __restrict__ Wo,
    const float* __restrict__ W2, const float* __restrict__ We,
    const float* __restrict__ b2, const float* __restrict__ be,
    ushort* __restrict__ Qb, ushort* __restrict__ Kb,
    ushort* __restrict__ VWot, ushort* __restrict__ KA,
    ushort* __restrict__ QB, float* __restrict__ W2e, float* __restrict__ b2e)
{
    __shared__ ushort sv[8][33];
    const int t = blockIdx.x * 256 + threadIdx.x;
    const int i = t >> 5;
    const int h = t & 31;
    const float* z = Z + (size_t)i * ZC;

    float q = bq[h], k = bk[h], v = bv[h];
#pragma unroll
    for (int d = 0; d < D_IN; ++d) {
        float zf = z[d];
        q = fmaf(zf, Wq[d * HID + h], q);
        k = fmaf(zf, Wk[d * HID + h], k);
        v = fmaf(zf, Wv[d * HID + h], v);
    }
    const float QS = 0.17677669529663687f * 1.4426950408889634f; // log2e/sqrt(32)
    Qb[(size_t)i * HID + h] = f2bf(q * QS);
    Kb[(size_t)i * HID + h] = f2bf(k);
    sv[threadIdx.x >> 5][h] = f2bf(v);

    if (h == 0) {
        float p0 = z[D_IN], p1 = z[D_IN + 1], p2 = z[D_IN + 2];
        const float C2 = 1.4426950408889634f / 0.18f;   // log2e/(2*sigma^2)
        const float SC = sqrtf(2.0f * C2);
        float px = p0 * SC, py = p1 * SC, pz = p2 * SC;
        float w  = -C2 * (p0 * p0 + p1 * p1 + p2 * p2);
        ushort phx = f2bf(px), phy = f2bf(py), phz = f2bf(pz);
        ushort plx = f2bf(px - bf2f(phx));
        ushort ply = f2bf(py - bf2f(phy));
        ushort plz = f2bf(pz - bf2f(phz));
        ushort wh  = f2bf(w);
        ushort wl  = f2bf(w - bf2f(wh));
        // negate j-side (KA) => MFMA result = +D
        ushort nhx = phx ^ 0x8000, nhy = phy ^ 0x8000, nhz = phz ^ 0x8000;
        ushort nlx = plx ^ 0x8000, nly = ply ^ 0x8000, nlz = plz ^ 0x8000;
        ushort nwh = wh ^ 0x8000,  nwl = wl ^ 0x8000;
        const ushort one = 0x3F80, none = 0xBF80;
        ushort ka0[8] = {nwh, nwl, none, none, nhx, nhy, nhz, nhx};
        ushort ka1[8] = {nhy, nhz, nlx, nly, nlz, nlx, nly, nlz};
        ushort qb0[8] = {one, one, wh, wl, phx, phy, phz, plx};
        ushort qb1[8] = {ply, plz, phx, phy, phz, plx, ply, plz};
        *(uint4*)&KA[(size_t)i * 8]       = *(uint4*)ka0;
        *(uint4*)&KA[((size_t)N + i) * 8] = *(uint4*)ka1;
        *(uint4*)&QB[(size_t)i * 8]       = *(uint4*)qb0;
        *(uint4*)&QB[((size_t)N + i) * 8] = *(uint4*)qb1;
    }

    // W2e = W2 @ We  (+ b2e) over the first 15 blocks
    if (blockIdx.x < 15) {
        int idx = blockIdx.x * 256 + threadIdx.x;      // 0..3839
        int f = idx / 30, o = idx - f * 30;
        float acc = 0.f;
#pragma unroll
        for (int d = 0; d < D_OUT; ++d)
            acc = fmaf(W2[f * D_OUT + d], We[d * D_OUT + o], acc);
        W2e[idx] = acc;
        if (idx < D_OUT) {
            float a2 = be[idx];
#pragma unroll
            for (int d = 0; d < D_OUT; ++d)
                a2 = fmaf(b2[d], We[d * D_OUT + idx], a2);
            b2e[idx] = a2;
        }
    }

    __syncthreads();
    // VWo^T: row c (0..29) = (V@Wo) col c; row 30 = 0; row 31 = 1.0
    const int io = threadIdx.x >> 5, c = threadIdx.x & 31;
    const int ii = blockIdx.x * 8 + io;
    float val;
    if (c < 30) {
        float acc = 0.f;
#pragma unroll
        for (int hh = 0; hh < HID; ++hh)
            acc = fmaf(bf2f(sv[io][hh]), Wo[hh * D_OUT + c], acc);
        val = acc;
    } else {
        val = (c == 31) ? 1.0f : 0.f;
    }
    VWot[(size_t)c * N + ii] = f2bf(val);
}

// ---------------------------------------------------------------------------
// Kernel B (R21, session-best): dbuf LDS (one barrier/chunk), reg prefetch,
// bounded gate a = 2^-D * rcp(1 + 2^-S'), bf16 partial, setprio around MFMA.
// ---------------------------------------------------------------------------
__global__ __launch_bounds__(256, 2) void dv_attn_kernel(
    const ushort* __restrict__ Qb, const ushort* __restrict__ Kb,
    const ushort* __restrict__ VWot, const ushort* __restrict__ KA,
    const ushort* __restrict__ QB, ushort* __restrict__ partial)
{
    __shared__ ushort lK[2][128 * 32];    // K tiles, 16B-chunk rot swizzle
    __shared__ ushort lV[2][32 * 128];    // VWo^T tiles, 8B-chunk XOR swizzle
    __shared__ ushort lKA[2][2][128 * 8]; // gate A-side aug

    const int tid  = threadIdx.x;
    const int lane = tid & 63;
    const int wv   = tid >> 6;
    const int h2   = lane >> 5;
    const int l31  = lane & 31;
    const int rb   = blockIdx.x & 63;
    const int jg   = blockIdx.x >> 6;
    const int i0w  = rb * 128 + wv * 32;

    const ushort* qp = Qb + (size_t)(i0w + l31) * HID + h2 * 8;
    const short8 qf0 = *(const short8*)qp;
    const short8 qf1 = *(const short8*)(qp + 16);
    const short8 qaug = *(const short8*)&QB[((size_t)h2 * N + i0w + l31) * 8];

    f32x16 zacc, oacc;
#pragma unroll
    for (int r = 0; r < 16; ++r) { zacc[r] = 0.f; oacc[r] = 0.f; }

    const int cA0 = (h2 + (l31 >> 1)) & 3;
    const int cA1 = (cA0 + 2) & 3;

    // staging indices (fixed per thread)
    const int kjr0 = tid >> 2,          kcc0 = tid & 3;
    const int kjr1 = (tid + 256) >> 2,  kcc1 = (tid + 256) & 3;
    const int kc20 = (kcc0 + (kjr0 >> 1)) & 3;
    const int kc21 = (kcc1 + (kjr1 >> 1)) & 3;
    const int vhh[4] = { tid >> 5, (tid + 256) >> 5, (tid + 512) >> 5, (tid + 768) >> 5 };
    const int vcx = tid & 31;
    const int ahalf = tid >> 7, ajj = tid & 127;

    uint4 kreg[2];
    uint2 vreg[4];
    uint4 kareg;

    auto LOADC = [&](int c) {
        const int j0 = (jg * NCH + c) << 7;
        kreg[0] = *(const uint4*)&Kb[(size_t)(j0 + kjr0) * HID + kcc0 * 8];
        kreg[1] = *(const uint4*)&Kb[(size_t)(j0 + kjr1) * HID + kcc1 * 8];
#pragma unroll
        for (int r2 = 0; r2 < 4; ++r2)
            vreg[r2] = *(const uint2*)&VWot[(size_t)vhh[r2] * N + j0 + vcx * 4];
        kareg = *(const uint4*)&KA[((size_t)ahalf * N + j0 + ajj) * 8];
    };
    auto WRITEC = [&](int b) {
        *(uint4*)&lK[b][kjr0 * 32 + kc20 * 8] = kreg[0];
        *(uint4*)&lK[b][kjr1 * 32 + kc21 * 8] = kreg[1];
#pragma unroll
        for (int r2 = 0; r2 < 4; ++r2)
            *(uint2*)&lV[b][vhh[r2] * 128 + (vcx ^ vhh[r2]) * 4] = vreg[r2];
        *(uint4*)&lKA[b][ahalf][ajj * 8] = kareg;
    };

    // prologue: chunk 0 -> buf 0
    LOADC(0);
    WRITEC(0);

#pragma unroll
    for (int ch = 0; ch < NCH; ++ch) {
        const int cur = ch & 1;
        if (ch + 1 < NCH) LOADC(ch + 1);   // issue early; lands under compute
        __syncthreads();                    // buf[cur] ready; prev reads done

        __builtin_amdgcn_s_setprio(1);
#pragma unroll
        for (int t32 = 0; t32 < 4; ++t32) {
            const ushort* krow = &lK[cur][(t32 * 32 + l31) * 32];
            short8 kf0 = *(const short8*)&krow[cA0 * 8];
            short8 kf1 = *(const short8*)&krow[cA1 * 8];
            f32x16 s = __builtin_amdgcn_mfma_f32_32x32x16_bf16(kf0, qf0, zacc, 0, 0, 0);
            s = __builtin_amdgcn_mfma_f32_32x32x16_bf16(kf1, qf1, s, 0, 0, 0);

            short8 kaug = *(const short8*)&lKA[cur][h2][(t32 * 32 + l31) * 8];
            f32x16 gA = __builtin_amdgcn_mfma_f32_32x32x16_bf16(kaug, qaug, zacc, 0, 0, 0);

            uint32_t pk[8];
#pragma unroll
            for (int p = 0; p < 8; ++p) {
                // a = 2^-D * rcp(1 + 2^-S'); D >= -eps, all factors bounded
                float eg0 = __builtin_amdgcn_exp2f(-gA[2 * p]);
                float es0 = __builtin_amdgcn_exp2f(-s[2 * p]);
                float a0  = eg0 * __builtin_amdgcn_rcpf(1.0f + es0);
                float eg1 = __builtin_amdgcn_exp2f(-gA[2 * p + 1]);
                float es1 = __builtin_amdgcn_exp2f(-s[2 * p + 1]);
                float a1  = eg1 * __builtin_amdgcn_rcpf(1.0f + es1);
                asm("v_cvt_pk_bf16_f32 %0, %1, %2" : "=v"(pk[p]) : "v"(a0), "v"(a1));
            }
            union BV { uint32_t u[4]; short8 v; };
            BV fa, fb;
            fa.u[0] = pk[0]; fa.u[1] = pk[1]; fa.u[2] = pk[2]; fa.u[3] = pk[3];
            fb.u[0] = pk[4]; fb.u[1] = pk[5]; fb.u[2] = pk[6]; fb.u[3] = pk[7];

            const ushort* vrow = &lV[cur][l31 * 128];
            const int cb = t32 * 8 + h2;
            BV b0, b1;
            *(uint2*)&b0.u[0] = *(const uint2*)&vrow[((cb    ) ^ l31) * 4];
            *(uint2*)&b0.u[2] = *(const uint2*)&vrow[((cb + 2) ^ l31) * 4];
            *(uint2*)&b1.u[0] = *(const uint2*)&vrow[((cb + 4) ^ l31) * 4];
            *(uint2*)&b1.u[2] = *(const uint2*)&vrow[((cb + 6) ^ l31) * 4];

            oacc = __builtin_amdgcn_mfma_f32_32x32x16_bf16(fa.v, b0.v, oacc, 0, 0, 0);
            oacc = __builtin_amdgcn_mfma_f32_32x32x16_bf16(fb.v, b1.v, oacc, 0, 0, 0);
        }
        __builtin_amdgcn_s_setprio(0);

        if (ch + 1 < NCH) WRITEC(cur ^ 1);  // fill other buffer; overlaps
    }

    // partial[i][jg*32 + c] (bf16): c<30 = raw pre-Wo H, c==31 = rowsum
#pragma unroll
    for (int r = 0; r < 16; ++r) {
        int ir = (r & 3) + 8 * (r >> 2) + 4 * h2 + i0w;
        partial[(size_t)ir * (JGC * 32) + jg * 32 + l31] = f2bf(oacc[r]);
    }
}

// ---------------------------------------------------------------------------
// Kernel C: epilogue v4 — wave-per-row, zero __syncthreads, bf16 partial in.
// ---------------------------------------------------------------------------
__global__ __launch_bounds__(256) void dv_epilogue_kernel(
    const ushort* __restrict__ partial,
    const float* __restrict__ bo,
    const float* __restrict__ ln_g, const float* __restrict__ ln_b,
    const float* __restrict__ W1, const float* __restrict__ b1,
    const float* __restrict__ W2e, const float* __restrict__ b2e,
    float* __restrict__ out)
{
    __shared__ float shf[4][FFD];    // per-wave private silu slice

    const int tid  = threadIdx.x;
    const int wv   = tid >> 6;
    const int lane = tid & 63;
    const int row  = blockIdx.x * 4 + wv;
    const int c    = lane & 31;
    const int half = lane >> 5;
    const bool a30 = c < 30;
    const int  c30 = a30 ? c : 0;

    // P1: row's 512 bf16 partials; lane reads 8 (stride 64), fold lane^32.
    float s8 = 0.f;
    {
        const ushort* pp = partial + (size_t)row * (JGC * 32) + lane;
#pragma unroll
        for (int q = 0; q < 8; ++q) s8 += bf2f(pp[q * 64]);
    }
    float sv = s8 + __shfl_xor(s8, 32, 64);   // col sums, dup in both halves

    float rsum = __shfl(sv, 31, 32);          // col 31 = rowsum
    float inv  = __builtin_amdgcn_rcpf(rsum + 1e-8f);
    float Hl   = a30 ? fmaf(sv, inv, bo[c30]) : 0.f;

    // LayerNorm in-register (width-32; lanes with c>=30 contribute 0)
    float x = Hl;
#pragma unroll
    for (int m = 1; m < 32; m <<= 1) x += __shfl_xor(x, m, 32);
    float mu = x * (1.0f / D_OUT);
    float d  = a30 ? (Hl - mu) : 0.f;
    float v2 = d * d;
#pragma unroll
    for (int m = 1; m < 32; m <<= 1) v2 += __shfl_xor(v2, m, 32);
    float rs = rsqrtf(v2 * (1.0f / D_OUT) + 1e-5f);
    float Hn = fmaf(d * rs, ln_g[c30], ln_b[c30]);  // valid where a30

    // FFN1 + SiLU: lane owns f = lane and f = lane + 64 (coalesced W1 rows)
    float acc0 = b1[lane], acc1 = b1[lane + 64];
#pragma unroll
    for (int o = 0; o < D_OUT; ++o) {
        float ho = rdlane(Hn, o);             // lane o < 30 holds Hn[o]
        acc0 = fmaf(ho, W1[o * FFD + lane], acc0);
        acc1 = fmaf(ho, W1[o * FFD + lane + 64], acc1);
    }
    const float L2E = 1.4426950408889634f;
    shf[wv][lane] =
        acc0 * __builtin_amdgcn_rcpf(1.0f + __builtin_amdgcn_exp2f(-acc0 * L2E));
    shf[wv][lane + 64] =
        acc1 * __builtin_amdgcn_rcpf(1.0f + __builtin_amdgcn_exp2f(-acc1 * L2E));
    // same-wave ds_write -> ds_read: ordered by lgkmcnt, no barrier needed

    // FFN2e: half-wave h covers f in [h*64, h*64+64); o = c30 per lane.
    float acc = 0.f;
    {
        const float* hbase = &shf[wv][half * 64];
#pragma unroll
        for (int k = 0; k < 16; ++k) {
            float4 hv = *(const float4*)&hbase[k * 4];
            const int f0 = half * 64 + k * 4;
            acc = fmaf(hv.x, W2e[(f0    ) * D_OUT + c30], acc);
            acc = fmaf(hv.y, W2e[(f0 + 1) * D_OUT + c30], acc);
            acc = fmaf(hv.z, W2e[(f0 + 2) * D_OUT + c30], acc);
            acc = fmaf(hv.w, W2e[(f0 + 3) * D_OUT + c30], acc);
        }
    }
    float val = acc + __shfl_xor(acc, 32, 64) + b2e[c30];

    if (lane < 32 && a30)
        out[(size_t)row * ZC + c] = val;

    float kep = (a30 && half == 0) ? val * val : 0.f;
#pragma unroll
    for (int m = 1; m < 32; m <<= 1) kep += __shfl_xor(kep, m, 32);
    if (lane == 0) {
        float* op = out + (size_t)row * ZC;
        op[30] = 0.f; op[31] = 0.f; op[32] = 0.f;
        op[33] = kep * (0.5f / D_OUT);
    }
}

// ---------------------------------------------------------------------------
extern "C" void kernel_launch(void* const* d_in, const int* in_sizes, int n_in,
                              void* d_out, int out_size, void* d_ws, size_t ws_size,
                              hipStream_t stream)
{
    const float* Z  = (const float*)d_in[1];
    const float* Wq = (const float*)d_in[2];
    const float* bq = (const float*)d_in[3];
    const float* Wk = (const float*)d_in[4];
    const float* bk = (const float*)d_in[5];
    const float* Wv = (const float*)d_in[6];
    const float* bv = (const float*)d_in[7];
    const float* Wo = (const float*)d_in[8];
    const float* bo = (const float*)d_in[9];
    const float* lg = (const float*)d_in[10];
    const float* lb = (const float*)d_in[11];
    const float* W1 = (const float*)d_in[12];
    const float* b1 = (const float*)d_in[13];
    const float* W2 = (const float*)d_in[14];
    const float* b2 = (const float*)d_in[15];
    const float* We = (const float*)d_in[16];
    const float* be = (const float*)d_in[17];
    float* out = (float*)d_out;

    ushort* Qb   = (ushort*)d_ws;                 // N*32 bf16
    ushort* Kb   = Qb + (size_t)N * HID;          // N*32 bf16
    ushort* VWot = Kb + (size_t)N * HID;          // [32][N] bf16 (V@Wo)^T
    ushort* KA   = VWot + (size_t)N * HID;        // [2][N][8] bf16
    ushort* QB   = KA + (size_t)N * 16;           // [2][N][8] bf16
    float*  W2e  = (float*)(QB + (size_t)N * 16); // [128][30]
    float*  b2e  = W2e + FFD * D_OUT;             // [30] (+pad)
    ushort* partial = (ushort*)(b2e + 32);        // [N][JGC*32] bf16

    hipLaunchKernelGGL(dv_qkv_kernel, dim3((N * HID) / 256), dim3(256), 0, stream,
                       Z, Wq, bq, Wk, bk, Wv, bv, Wo, W2, We, b2, be,
                       Qb, Kb, VWot, KA, QB, W2e, b2e);
    hipLaunchKernelGGL(dv_attn_kernel, dim3(64 * JGC), dim3(256), 0, stream,
                       Qb, Kb, VWot, KA, QB, partial);
    hipLaunchKernelGGL(dv_epilogue_kernel, dim3(N / 4), dim3(256), 0, stream,
                       partial, bo, lg, lb, W1, b1, W2e, b2e, out);
}